// Round 2
// baseline (97.042 us; speedup 1.0000x reference)
//
#include <hip/hip_runtime.h>
#include <math.h>

#define H_IMG 1024
#define W_IMG 1280
#define NPIX (H_IMG * W_IMG)
#define TPB 256

// ---------------------------------------------------------------------------
// Key insight: the reference's jnp.linalg.pinv(J) uses default
// rcond = 10 * max(M,N) * eps(f32) = 10 * 1310720 * 1.19e-7 ~= 1.56.
// The singular-value cutoff is 1.56 * sigma_max, which exceeds ALL singular
// values of any matrix. So pinv(J) == 0, x0 == 0, so3_exp(0) == I, and R
// stays exactly identity for all 5 iterations. The GN loop is a no-op.
// Outputs: R = I; warped = warp(ref, Hi(I)); res = mask * (warped - target).
// ---------------------------------------------------------------------------

__device__ inline float tap(const float* __restrict__ img, int yi, int xi, float wt) {
    bool valid = (xi >= 0) & (xi < W_IMG) & (yi >= 0) & (yi < H_IMG);
    int yc = min(max(yi, 0), H_IMG - 1);
    int xc = min(max(xi, 0), W_IMG - 1);
    float v = img[yc * W_IMG + xc];
    return valid ? v * wt : 0.0f;
}

__global__ __launch_bounds__(TPB) void k_all(const float* __restrict__ ref,
                                             const float* __restrict__ target,
                                             const float* __restrict__ mask,
                                             const float* __restrict__ K,
                                             float* __restrict__ outR,
                                             float* __restrict__ out_res,
                                             float* __restrict__ out_warp) {
    int idx = blockIdx.x * TPB + threadIdx.x;
    if (idx >= NPIX) return;

    // ---- Hi = inv(K @ I @ inv(K)) mimicking the reference's f32 path ----
    // (uniform scalar work per thread; ~60 flops, negligible)
    float f  = K[0], cu = K[2];
    float f2 = K[4], cv = K[5];
    float Ki00 = 1.0f / f,  Ki02 = -cu / f;
    float Ki11 = 1.0f / f2, Ki12 = -cv / f2;
    // Hm = K @ Kinv  (R = I), f32 like the reference
    float Hm0 = f * Ki00;
    float Hm2 = f * Ki02 + cu;
    float Hm4 = f2 * Ki11;
    float Hm5 = f2 * Ki12 + cv;
    // generic adjugate inverse (double) of Hm = [[Hm0,0,Hm2],[0,Hm4,Hm5],[0,0,1]]
    double a = Hm0, b = 0.0, c = Hm2;
    double d = 0.0, e = Hm4, g = Hm5;
    double h = 0.0, i2 = 0.0, j2 = 1.0;
    double C00 = e * j2 - g * i2;
    double C01 = -(d * j2 - g * h);
    double C02 = d * i2 - e * h;
    double C10 = -(b * j2 - c * i2);
    double C11 = a * j2 - c * h;
    double C12 = -(a * i2 - b * h);
    double C20 = b * g - c * e;
    double C21 = -(a * g - c * d);
    double C22 = a * e - b * d;
    double det = a * C00 + b * C01 + c * C02;
    double inv = 1.0 / det;
    float h0 = (float)(C00 * inv), h1 = (float)(C10 * inv), h2 = (float)(C20 * inv);
    float h3 = (float)(C01 * inv), h4 = (float)(C11 * inv), h5 = (float)(C21 * inv);
    float h6 = (float)(C02 * inv), h7 = (float)(C12 * inv), h8 = (float)(C22 * inv);

    // ---- warp (bilinear, zeros outside) ----
    float u = (float)(idx % W_IMG);
    float v = (float)(idx / W_IMG);
    float den = h6 * u + h7 * v + h8;
    float xs = (h0 * u + h1 * v + h2) / den;
    float ys = (h3 * u + h4 * v + h5) / den;
    float x0f = floorf(xs), y0f = floorf(ys);
    float wx = xs - x0f, wy = ys - y0f;
    int x0 = (int)x0f, y0 = (int)y0f;
    float acc = 0.0f;
    acc += tap(ref, y0,     x0,     (1.f - wx) * (1.f - wy));
    acc += tap(ref, y0,     x0 + 1, wx * (1.f - wy));
    acc += tap(ref, y0 + 1, x0,     (1.f - wx) * wy);
    acc += tap(ref, y0 + 1, x0 + 1, wx * wy);

    out_warp[idx] = acc;
    out_res[idx] = mask[idx] * (acc - target[idx]);

    // ---- R = I ----
    if (idx < 9) {
        outR[idx] = ((idx & 3) == 0) ? 1.0f : 0.0f;  // idx 0,4,8 diagonal
    }
}

extern "C" void kernel_launch(void* const* d_in, const int* in_sizes, int n_in,
                              void* d_out, int out_size, void* d_ws, size_t ws_size,
                              hipStream_t stream) {
    const float* ref_img = (const float*)d_in[0];
    const float* target  = (const float*)d_in[1];
    const float* mask    = (const float*)d_in[2];
    const float* K       = (const float*)d_in[3];
    // d_in[4] (batch_proj_jac) unused: pinv cutoff makes x0 == 0 identically.

    float* out      = (float*)d_out;
    float* out_R    = out;             // 9
    float* out_res  = out + 9;         // NPIX
    float* out_warp = out + 9 + NPIX;  // NPIX

    k_all<<<NPIX / TPB, TPB, 0, stream>>>(ref_img, target, mask, K,
                                          out_R, out_res, out_warp);
}